// Round 14
// baseline (71.139 us; speedup 1.0000x reference)
//
#include <hip/hip_runtime.h>
#include <hip/hip_bf16.h>

#define B_ROWS 8192
#define DIM 256
#define C_CLS 5994
#define N_CHUNK 188       // 6016 / 32
#define NSPL 16
#define NPACK 444         // 256 emb-tiles + 188 W-tiles
#define NDAS 128
#define NMERGE 512
#define H_HALF 4096
#define SCALE_F 30.0f
#define MAXL 30.0f
#define EXPC 43.2808512266689f   // 30*log2(e):  exp(30x-30) = exp2(EXPC*x - EXPC)

#if defined(__has_builtin)
#if __has_builtin(__builtin_amdgcn_exp2f)
#define EXP2(x) __builtin_amdgcn_exp2f(x)
#endif
#endif
#ifndef EXP2
#define EXP2(x) exp2f(x)
#endif

typedef float f32x16 __attribute__((ext_vector_type(16)));
typedef long long ll;
typedef ll ll2 __attribute__((ext_vector_type(2)));

// ---------------- pack: norms + blocked FP8 layouts + cnt zero -----------
// FP8 blocked layout per 32-row tile (8 KB), PAIRED frags so loads stay 16B:
// pair j (=frags 2j,2j+1): byte = j*1024 + h*512 + row*16 + slot*8 + idx.
// A wave's paired-frag load is lane-linear -> one contiguous 1 KB load.
__global__ __launch_bounds__(256)
void k_pack(const float* __restrict__ emb, const float* __restrict__ W,
            char* __restrict__ en_blk, char* __restrict__ wn_blk,
            float* __restrict__ rne, float* __restrict__ rnw,
            unsigned* __restrict__ cnt) {
  __shared__ float ssm[256];
  __shared__ float rnl[32];
  const int b = blockIdx.x;
  const int t = threadIdx.x;
  if (b == 0 && t == 0) *cnt = 0u;       // completion counter for k_tail (poison-safe)
  const bool isW = b >= (B_ROWS/32);
  const int tile = isW ? b - (B_ROWS/32) : b;
  const int l31 = t & 31;
  const int row = tile*32 + l31;
  const float* __restrict__ src = isW ? W : emb;
  const bool rv = (!isW) || (row < C_CLS);

  float v[4][8];
  float ss = 0.f;
  #pragma unroll
  for (int i=0;i<4;i++) {
    const int d0 = ((t>>6) + i*4)*16 + ((t>>5)&1)*8;
    if (rv) {
      float4 x0 = *(const float4*)(src + (size_t)row*DIM + d0);
      float4 x1 = *(const float4*)(src + (size_t)row*DIM + d0 + 4);
      v[i][0]=x0.x; v[i][1]=x0.y; v[i][2]=x0.z; v[i][3]=x0.w;
      v[i][4]=x1.x; v[i][5]=x1.y; v[i][6]=x1.z; v[i][7]=x1.w;
      ss += x0.x*x0.x + x0.y*x0.y + x0.z*x0.z + x0.w*x0.w
          + x1.x*x1.x + x1.y*x1.y + x1.z*x1.z + x1.w*x1.w;
    } else {
      #pragma unroll
      for (int j=0;j<8;j++) v[i][j] = 0.f;
    }
  }
  ssm[t] = ss;
  __syncthreads();
  if (t < 32) {
    float s = 0.f;
    #pragma unroll
    for (int j=0;j<8;j++) s += ssm[t + j*32];
    float rn = 1.0f/(sqrtf(s) + 1e-12f);
    rnl[t] = rn;
    int rw = tile*32 + t;
    if (!isW) rne[rw] = rn;
    else if (rw < C_CLS) rnw[rw] = rn;
  }
  __syncthreads();
  const float rn = rnl[l31];
  char* __restrict__ dst = (isW ? wn_blk : en_blk) + (size_t)tile*8192;
  #pragma unroll
  for (int i=0;i<4;i++) {
    const int kk = (t>>6) + i*4;
    const int off = (kk>>1)*1024 + ((t>>5)&1)*512 + l31*16 + (kk&1)*8;
    int d0 = 0, d1 = 0;
    d0 = __builtin_amdgcn_cvt_pk_fp8_f32(v[i][0]*rn, v[i][1]*rn, d0, false);
    d0 = __builtin_amdgcn_cvt_pk_fp8_f32(v[i][2]*rn, v[i][3]*rn, d0, true);
    d1 = __builtin_amdgcn_cvt_pk_fp8_f32(v[i][4]*rn, v[i][5]*rn, d1, false);
    d1 = __builtin_amdgcn_cvt_pk_fp8_f32(v[i][6]*rn, v[i][7]*rn, d1, true);
    uint2 u; u.x = (unsigned)d0; u.y = (unsigned)d1;
    *(uint2*)(dst + off) = u;
  }
}

// ---------------- das: pair distances, per-block partial slots -----------
__global__ __launch_bounds__(256)
void k_das(const float* __restrict__ emb, const int* __restrict__ y_d,
           float* __restrict__ dasL, float* __restrict__ dasD) {
  __shared__ float s0[4], s1[4];
  const int wid = threadIdx.x >> 6, lane = threadIdx.x & 63;
  float a2 = 0.f, a3 = 0.f;
  for (int i = blockIdx.x*4 + wid; i < H_HALF; i += NDAS*4) {
    const int j = (i+1) & (H_HALF-1);
    const int di = y_d[i], dj = y_d[j], dih = y_d[i + H_HALF];
    float4 z = {0.f,0.f,0.f,0.f};
    float4 mi = (di==0)  ? *(const float4*)(emb + (size_t)i*DIM + lane*4) : z;
    float4 mj = (dj==0)  ? *(const float4*)(emb + (size_t)j*DIM + lane*4) : z;
    float4 ti = (dih!=0) ? *(const float4*)(emb + (size_t)(i+H_HALF)*DIM + lane*4)
                         : ((di!=0) ? *(const float4*)(emb + (size_t)i*DIM + lane*4) : z);
    float px = mi.x-mj.x, py = mi.y-mj.y, pz = mi.z-mj.z, pw = mi.w-mj.w;
    float nx = mi.x-ti.x, ny = mi.y-ti.y, nz = mi.z-ti.z, nw = mi.w-ti.w;
    float sp = px*px+py*py+pz*pz+pw*pw;
    float sn = nx*nx+ny*ny+nz*nz+nw*nw;
    #pragma unroll
    for (int off=1; off<64; off<<=1) { sp += __shfl_xor(sp, off); sn += __shfl_xor(sn, off); }
    if (lane == 0) {
      float dp = sqrtf(sp), dn = sqrtf(sn);
      float m = fmaxf(2.0f - dp, 0.f);
      a2 += m*m + dn*dn;
      a3 += dp + dn;
    }
  }
  if (lane == 0) { s0[wid] = a2; s1[wid] = a3; }
  __syncthreads();
  if (threadIdx.x == 0) {
    dasL[blockIdx.x] = s0[0]+s0[1]+s0[2]+s0[3];   // own slot, plain store
    dasD[blockIdx.x] = s1[0]+s1[1]+s1[2]+s1[3];
  }
}

// ---------------- main fused GEMM + online softmax-stats (FP8) ----------
// grid = 64 panels x 16 splits = 1024 blocks (4/CU); block = 256 (4 waves).
// Barrier-free; B register-double-buffered; peeled last iteration.
__global__ __launch_bounds__(256, 2)
void k_logits(const char* __restrict__ en_blk, const char* __restrict__ wn_blk,
              float* __restrict__ psum, unsigned* __restrict__ pkey) {
  const int split = blockIdx.x & (NSPL-1);
  const int panel = blockIdx.x / NSPL;
  const int wid  = threadIdx.x >> 6;
  const int lane = threadIdx.x & 63;
  const int l31  = lane & 31;
  const int tile = panel*4 + wid;

  // A paired-frags: 8 contiguous 1 KB wave-loads, resident all loop
  ll2 a[8];
  const char* ab = en_blk + (size_t)tile*8192 + lane*16;
  #pragma unroll
  for (int j=0;j<8;j++) a[j] = *(const ll2*)(ab + j*1024);

  float ssum[16]; unsigned key[16];
  #pragma unroll
  for (int r=0;r<16;r++){ ssum[r]=0.f; key[r]=0u; }

  const int nit = (N_CHUNK - split + NSPL - 1) / NSPL;   // 12 or 11
  const char* p = wn_blk + (size_t)split*8192 + lane*16;
  const ptrdiff_t STEP = (ptrdiff_t)NSPL*8192;

  ll2 b0[4], b1[4];
  #pragma unroll
  for (int j=0;j<4;j++) b0[j] = *(const ll2*)(p + j*1024);
  #pragma unroll
  for (int j=0;j<4;j++) b1[j] = *(const ll2*)(p + (j+4)*1024);

  unsigned colu = (unsigned)(split*32 + l31);
  for (int it = 0; it < nit-1; ++it) {
    const char* pn = p + STEP;
    f32x16 acc = {};
    #pragma unroll
    for (int j=0;j<4;j++) {
      acc = __builtin_amdgcn_mfma_f32_32x32x16_fp8_fp8(a[j][0], b0[j][0], acc, 0,0,0);
      acc = __builtin_amdgcn_mfma_f32_32x32x16_fp8_fp8(a[j][1], b0[j][1], acc, 0,0,0);
    }
    #pragma unroll
    for (int j=0;j<4;j++) b0[j] = *(const ll2*)(pn + j*1024);
    #pragma unroll
    for (int j=0;j<4;j++) {
      acc = __builtin_amdgcn_mfma_f32_32x32x16_fp8_fp8(a[j+4][0], b1[j][0], acc, 0,0,0);
      acc = __builtin_amdgcn_mfma_f32_32x32x16_fp8_fp8(a[j+4][1], b1[j][1], acc, 0,0,0);
    }
    #pragma unroll
    for (int j=0;j<4;j++) b1[j] = *(const ll2*)(pn + (j+4)*1024);
    // epilogue: pad cols are zero rows -> x=0 -> exp2(-43.3)~1e-13, negligible
    #pragma unroll
    for (int r=0;r<16;r++) {
      float x = acc[r];                       // cosine in [-1,1] (+fp8 noise)
      ssum[r] += EXP2(fmaf(x, EXPC, -EXPC));
      unsigned ky = (__float_as_uint(x + 2.0f) & 0xFFFFE000u) | colu;  // x+2>0: monotone
      key[r] = ky > key[r] ? ky : key[r];
    }
    colu += NSPL*32;
    p = pn;
  }
  { // last chunk, no prefetch
    f32x16 acc = {};
    #pragma unroll
    for (int j=0;j<4;j++) {
      acc = __builtin_amdgcn_mfma_f32_32x32x16_fp8_fp8(a[j][0], b0[j][0], acc, 0,0,0);
      acc = __builtin_amdgcn_mfma_f32_32x32x16_fp8_fp8(a[j][1], b0[j][1], acc, 0,0,0);
    }
    #pragma unroll
    for (int j=0;j<4;j++) {
      acc = __builtin_amdgcn_mfma_f32_32x32x16_fp8_fp8(a[j+4][0], b1[j][0], acc, 0,0,0);
      acc = __builtin_amdgcn_mfma_f32_32x32x16_fp8_fp8(a[j+4][1], b1[j][1], acc, 0,0,0);
    }
    #pragma unroll
    for (int r=0;r<16;r++) {
      float x = acc[r];
      ssum[r] += EXP2(fmaf(x, EXPC, -EXPC));
      unsigned ky = (__float_as_uint(x + 2.0f) & 0xFFFFE000u) | colu;
      key[r] = ky > key[r] ? ky : key[r];
    }
  }

  // reduce across the 32 lanes (cols)
  #pragma unroll
  for (int off=1; off<32; off<<=1) {
    #pragma unroll
    for (int r=0;r<16;r++) {
      ssum[r] += __shfl_xor(ssum[r], off);
      unsigned o = __shfl_xor(key[r], off);
      key[r] = o > key[r] ? o : key[r];
    }
  }
  if (l31 == 0) {
    const int rowbase = tile*32;
    #pragma unroll
    for (int r=0;r<16;r++) {
      int row = rowbase + (r&3) + 8*(r>>2) + 4*(lane>>5);
      psum[(size_t)row*NSPL + split] = ssum[r];   // [row][split]: coalesced gather in merge
      pkey[(size_t)row*NSPL + split] = key[r];
    }
  }
}

// ---------------- tail: merge + finalize (per-block slots, no hot atomics)
__global__ __launch_bounds__(256)
void k_tail(const float* __restrict__ emb, const float* __restrict__ W,
            const int* __restrict__ y,
            const float* __restrict__ rne, const float* __restrict__ rnw,
            const float* __restrict__ psum, const unsigned* __restrict__ pkey,
            float* __restrict__ lossP, float* __restrict__ corrP,
            const float* __restrict__ dasL, const float* __restrict__ dasD,
            unsigned* __restrict__ cnt, float* __restrict__ out) {
  __shared__ float s0[4], s1[4];
  __shared__ int isLast;
  const int wid = threadIdx.x >> 6, lane = threadIdx.x & 63;
  float lacc = 0.f, cacc = 0.f;
  for (int row = blockIdx.x*4 + wid; row < B_ROWS; row += NMERGE*4) {
    const int yc = y[row];
    float4 e = *(const float4*)(emb + (size_t)row*DIM + lane*4);
    float4 w = *(const float4*)(W + (size_t)yc*DIM + lane*4);
    float d = e.x*w.x + e.y*w.y + e.z*w.z + e.w*w.w;
    #pragma unroll
    for (int off=1; off<64; off<<=1) d += __shfl_xor(d, off);
    float S = 0.f; unsigned km = 0u;
    if (lane < NSPL) {                       // one 64 B contiguous gather
      S = psum[(size_t)row*NSPL + lane];
      km = pkey[(size_t)row*NSPL + lane];
    }
    #pragma unroll
    for (int off=1; off<NSPL; off<<=1) {
      S += __shfl_xor(S, off);
      unsigned o = __shfl_xor(km, off);
      if (o > km) km = o;
    }
    if (lane == 0) {
      float ly = SCALE_F * d * rne[row] * rnw[yc];
      lacc += MAXL + logf(S) - ly;
      cacc += ((km & 0x1FFFu) == (unsigned)yc) ? 1.f : 0.f;
    }
  }
  if (lane == 0) { s0[wid] = lacc; s1[wid] = cacc; }
  __syncthreads();
  if (threadIdx.x == 0) {
    lossP[blockIdx.x] = s0[0]+s0[1]+s0[2]+s0[3];  // own slot, plain store
    corrP[blockIdx.x] = s1[0]+s1[1]+s1[2]+s1[3];
    __threadfence();                               // publish before counting
    unsigned done = atomicAdd(cnt, 1u);
    isLast = (done == NMERGE-1u) ? 1 : 0;
  }
  __syncthreads();
  if (isLast) {
    // 256 threads reduce all partials; slots read via coherent atomic-reads
    const int t = threadIdx.x;
    float lv = atomicAdd(&lossP[t], 0.f) + atomicAdd(&lossP[t+256], 0.f);
    float cv = atomicAdd(&corrP[t], 0.f) + atomicAdd(&corrP[t+256], 0.f);
    float dl = (t < NDAS) ? atomicAdd((float*)&dasL[t], 0.f) : 0.f;
    float dd = (t < NDAS) ? atomicAdd((float*)&dasD[t], 0.f) : 0.f;
    #pragma unroll
    for (int off=1; off<64; off<<=1) {
      lv += __shfl_xor(lv, off); cv += __shfl_xor(cv, off);
      dl += __shfl_xor(dl, off); dd += __shfl_xor(dd, off);
    }
    __shared__ float r4[4][4];
    if (lane == 0) { r4[wid][0]=lv; r4[wid][1]=cv; r4[wid][2]=dl; r4[wid][3]=dd; }
    __syncthreads();
    if (t == 0) {
      out[0] = (r4[0][0]+r4[1][0]+r4[2][0]+r4[3][0]) * (1.0f/B_ROWS);  // loss_c
      out[1] = (r4[0][2]+r4[1][2]+r4[2][2]+r4[3][2]) * (1.0f/B_ROWS);  // das_loss
      out[2] = (r4[0][1]+r4[1][1]+r4[2][1]+r4[3][1]) * (1.0f/B_ROWS);  // acc
      out[3] = (r4[0][3]+r4[1][3]+r4[2][3]+r4[3][3]) * (1.0f/B_ROWS);  // das_dist_mean
    }
  }
}

extern "C" void kernel_launch(void* const* d_in, const int* in_sizes, int n_in,
                              void* d_out, int out_size, void* d_ws, size_t ws_size,
                              hipStream_t stream) {
  const float* emb = (const float*)d_in[0];
  const float* W   = (const float*)d_in[1];
  const int*   y   = (const int*)d_in[2];
  const int*   y_d = (const int*)d_in[3];

  char* ws = (char*)d_ws;
  const size_t EN_OFF   = 0;                                  // 256 tiles * 8 KB
  const size_t WN_OFF   = EN_OFF  + (size_t)256*8192;
  const size_t RNE_OFF  = WN_OFF  + (size_t)N_CHUNK*8192;
  const size_t RNW_OFF  = RNE_OFF + (size_t)B_ROWS*4;
  const size_t PSUM_OFF = RNW_OFF + 24064;
  const size_t PKEY_OFF = PSUM_OFF + (size_t)NSPL*B_ROWS*4;
  const size_t LP_OFF   = PKEY_OFF + (size_t)NSPL*B_ROWS*4;   // 512 f32
  const size_t CP_OFF   = LP_OFF   + NMERGE*4;                // 512 f32
  const size_t DL_OFF   = CP_OFF   + NMERGE*4;                // 128 f32
  const size_t DD_OFF   = DL_OFF   + NDAS*4;                  // 128 f32
  const size_t CNT_OFF  = DD_OFF   + NDAS*4;                  // 4 B (+pad)

  char*     en_blk = ws + EN_OFF;
  char*     wn_blk = ws + WN_OFF;
  float*    rne   = (float*)(ws + RNE_OFF);
  float*    rnw   = (float*)(ws + RNW_OFF);
  float*    psum  = (float*)(ws + PSUM_OFF);
  unsigned* pkey  = (unsigned*)(ws + PKEY_OFF);
  float*    lossP = (float*)(ws + LP_OFF);
  float*    corrP = (float*)(ws + CP_OFF);
  float*    dasL  = (float*)(ws + DL_OFF);
  float*    dasD  = (float*)(ws + DD_OFF);
  unsigned* cnt   = (unsigned*)(ws + CNT_OFF);

  k_pack<<<NPACK, 256, 0, stream>>>(emb, W, en_blk, wn_blk, rne, rnw, cnt);
  k_das<<<NDAS, 256, 0, stream>>>(emb, y_d, dasL, dasD);
  k_logits<<<64*NSPL, 256, 0, stream>>>(en_blk, wn_blk, psum, pkey);
  k_tail<<<NMERGE, 256, 0, stream>>>(emb, W, y, rne, rnw, psum, pkey,
                                     lossP, corrP, dasL, dasD, cnt, (float*)d_out);
}